// Round 17
// baseline (162.052 us; speedup 1.0000x reference)
//
#include <hip/hip_runtime.h>
#include <hip/hip_bf16.h>

#define NS 8192
#define NQ 8192
#define NTOT 16384
#define KDIM 1024
#define ED 512
#define NC 64

typedef __attribute__((ext_vector_type(4))) float fx4;
typedef __attribute__((ext_vector_type(8))) short sx8;
typedef __attribute__((ext_vector_type(4))) unsigned short ux4;
typedef __attribute__((ext_vector_type(8))) unsigned short ux8;

__device__ __forceinline__ unsigned short f2bf(float f) {
  union { float f; unsigned u; } v; v.f = f;
  unsigned r = v.u + 0x7fffu + ((v.u >> 16) & 1u);   // RNE
  return (unsigned short)(r >> 16);
}
__device__ __forceinline__ float bf2f(unsigned short h) {
  union { unsigned u; float f; } v; v.u = ((unsigned)h) << 16;
  return v.f;
}

// ---------------------------------------------------------------------------
// K0: W -> Wtp, bf16 in MFMA B-FRAGMENT-PACKED order (unchanged).
// Also zeroes rowssq and Pacc.
// ---------------------------------------------------------------------------
__global__ __launch_bounds__(256) void k_prep(
    const float* __restrict__ W, unsigned short* __restrict__ Wtp,
    float* __restrict__ rowssq, float* __restrict__ Pacc) {
  int c = blockIdx.x * 256 + threadIdx.x;   // 0..65535
  int lane = c & 63;
  int j    = (c >> 6) & 3;
  int s2   = (c >> 8) & 1;
  int kt   = (c >> 9) & 15;
  int n64  = c >> 13;
  int quad = lane >> 4, ml = lane & 15;
  int n  = n64 * 64 + j * 16 + ml;
  int kb = kt * 64 + (s2 * 4 + quad) * 8;
  ux8 o;
#pragma unroll
  for (int e = 0; e < 8; ++e) o[e] = f2bf(W[(size_t)(kb + e) * ED + n]);
  *(ux8*)&Wtp[(size_t)c * 8] = o;
  if (c < NTOT) rowssq[c] = 0.f;
  if (c < NC * ED) Pacc[c] = 0.f;
}

// ---------------------------------------------------------------------------
// K1: emb = bf16(X) @ W + per-row ssq.
// R16 POST-MORTEM: X-read-once cut 51->41us (first movement in 10 rounds;
// direction right, magnitude short). New regime: X traffic minimal, HBM 17%,
// MFMA 14%, occupancy 15% (grid 256 = exactly 1 block/CU) — every barrier
// idles the WHOLE CU; no independent work exists to overlap the 16
// barrier+drain windows. (R12's TLP-null was measured in the X-L3-BW-bound
// regime — rule #23: uninterpretable here.)
// R17: 2 blocks/CU. 32-row tiles, grid 512 (X still read exactly once).
// 8 waves of 32x64 (acc[2][4]); A-stage = 1 fx4/thread (512 thr x 16B,
// coalesced 256B row segments), ds_write_b64 with the same verified slot
// swizzle at half-octet granularity. launch_bounds(512,4) = 2 blocks/CU.
// Known cost: per-wave B re-reads double to 512MB L2 (~+7us, overlapped).
// Falsifiable: overlap-theory => 26-33us; invariant ~41 => intra-step serial.
// ---------------------------------------------------------------------------
__global__ __launch_bounds__(512, 4) void k_gemm_embed(
    const float* __restrict__ Xs, const float* __restrict__ Xq,
    const unsigned short* __restrict__ Wtp,
    unsigned short* __restrict__ emb, float* __restrict__ rowssq) {
  __shared__ unsigned short Ash[2][32 * 8 * 8];  // 4 KB per buf, [m*8+slot][8]

  int m_blk = blockIdx.x;          // 0..511, unique 32-row tile
  const float* Xsrc = (m_blk < 256)
      ? (Xs + (size_t)m_blk * 32 * KDIM)
      : (Xq + (size_t)(m_blk - 256) * 32 * KDIM);

  int t = threadIdx.x;             // 0..511
  int lane = t & 63, w = t >> 6;   // w = 0..7: 64-col slice (= n64 unit)
  int quad = lane >> 4, ml = lane & 15;

  // per-wave B fragment base: chunk (w*8192 + lane), element *8
  const unsigned short* Bbase = Wtp + ((size_t)w * 8192 + lane) * 8;

  fx4 acc[2][4];                   // wave's 32x64 output
#pragma unroll
  for (int i = 0; i < 2; ++i)
#pragma unroll
    for (int j = 0; j < 4; ++j) acc[i][j] = fx4{0.f, 0.f, 0.f, 0.f};

  fx4 avA, avB;                    // NAMED A double-buffer, 1 fx4/thread

  // A addressing: thread t covers row am, 16B sub-chunk (oct, half)
  int am = t >> 4;                 // 0..31
  int aoff = t & 15;               // 16B unit within the 64-k slice
  int aoct = aoff >> 1, ahalf = aoff & 1;

  auto loadA = [&](int kt, fx4& av) {
    av = *(const fx4*)&Xsrc[(size_t)am * KDIM + kt * 64 + aoff * 4];
  };
  auto writeA = [&](const fx4& av, int bbuf) {
    ux4 o;
    o[0] = f2bf(av.x); o[1] = f2bf(av.y); o[2] = f2bf(av.z); o[3] = f2bf(av.w);
    *(ux4*)&Ash[bbuf][((am * 8) + (aoct ^ (am & 7))) * 8 + ahalf * 4] = o;
  };
  auto loadB = [&](int kt, sx8 (&bf)[2][4]) {
#pragma unroll
    for (int s2 = 0; s2 < 2; ++s2)
#pragma unroll
      for (int j = 0; j < 4; ++j)
        bf[s2][j] = *(const sx8*)&Bbase[(size_t)(kt * 512 + s2 * 256 + j * 64) * 8];
  };
  auto compute = [&](int b, const sx8 (&bf)[2][4]) {
#pragma unroll
    for (int s2 = 0; s2 < 2; ++s2) {
      int kq = s2 * 4 + quad;
      sx8 af[2];
#pragma unroll
      for (int i = 0; i < 2; ++i) {
        int row = i * 16 + ml;
        af[i] = *(const sx8*)&Ash[b][(row * 8 + (kq ^ (row & 7))) * 8];
      }
#pragma unroll
      for (int i = 0; i < 2; ++i)
#pragma unroll
        for (int j = 0; j < 4; ++j)
          acc[i][j] = __builtin_amdgcn_mfma_f32_16x16x32_bf16(af[i], bf[s2][j], acc[i][j], 0, 0, 0);
    }
  };
  auto sync_step = [&]() {
    __builtin_amdgcn_sched_barrier(0);
    asm volatile("s_waitcnt lgkmcnt(0)" ::: "memory");
    __builtin_amdgcn_s_barrier();
    __builtin_amdgcn_sched_barrier(0);
  };

  // prologue: A(0)->avA->Ash[0]; A(1)->avB stays in flight
  loadA(0, avA);
  loadA(1, avB);
  writeA(avA, 0);
  sync_step();

  for (int it = 0; it < 8; ++it) {
    int kt0 = it * 2;
    {
      sx8 bf[2][4];
      loadB(kt0, bf);
      loadA(kt0 + 2 < 16 ? kt0 + 2 : 15, avA);
      compute(0, bf);
      writeA(avB, 1);
      sync_step();
    }
    {
      sx8 bf[2][4];
      loadB(kt0 + 1, bf);
      loadA(kt0 + 3 < 16 ? kt0 + 3 : 15, avB);
      compute(1, bf);
      writeA(avA, 0);
      sync_step();
    }
  }

  // epilogue: emb store + row-ssq partial (shfl width-16 + 1 atomic per row)
  int grow = m_blk * 32;
  int gcol = w * 64;
#pragma unroll
  for (int i = 0; i < 2; ++i) {
#pragma unroll
    for (int r = 0; r < 4; ++r) {
      int mrow = grow + i * 16 + quad * 4 + r;
      float p = 0.f;
#pragma unroll
      for (int j = 0; j < 4; ++j) {
        emb[(size_t)mrow * ED + gcol + j * 16 + ml] = f2bf(acc[i][j][r]);
        p += acc[i][j][r] * acc[i][j][r];
      }
#pragma unroll
      for (int off = 1; off < 16; off <<= 1) p += __shfl_xor(p, off, 16);
      if (ml == 0) atomicAdd(&rowssq[mrow], p);
    }
  }
}

// ---------------------------------------------------------------------------
// K2: per-class sums of (emb_s/||s||), LDS-accumulated, global-atomic flush
// into Pacc[NC][ED] (unchanged).
// ---------------------------------------------------------------------------
__global__ __launch_bounds__(256) void k_proto(
    const unsigned short* __restrict__ embS, const float* __restrict__ rowssq,
    const int* __restrict__ labels, float* __restrict__ Pacc) {
  __shared__ float Pl[NC * 64];  // 16 KB: [class][dim-within-slice]
  int t = threadIdx.x;
#pragma unroll
  for (int i = 0; i < 16; ++i) Pl[i * 256 + t] = 0.f;
  __syncthreads();

  int w = t >> 6, lane = t & 63;
  int ds = blockIdx.y;            // dim slice: dims [ds*64, ds*64+64)
  int row0 = blockIdx.x * 256;    // 32 chunks of 256 rows
#pragma unroll 4
  for (int r = w; r < 256; r += 4) {
    int row = row0 + r;
    int lbl = labels[row];
    float scale = 1.0f / fmaxf(sqrtf(rowssq[row]), 1e-12f);
    float v = bf2f(embS[(size_t)row * ED + ds * 64 + lane]) * scale;
    atomicAdd(&Pl[lbl * 64 + lane], v);
  }
  __syncthreads();

#pragma unroll
  for (int i = 0; i < 16; ++i) {
    int idx = i * 256 + t;        // class = idx>>6, dim-in-slice = idx&63
    atomicAdd(&Pacc[(size_t)(idx >> 6) * ED + ds * 64 + (idx & 63)], Pl[idx]);
  }
}

// ---------------------------------------------------------------------------
// K3: class_scores = (emb_q @ P^T) / ||q|| + fused softmax (unchanged R13:
// 128 blocks x 256 threads, block-shared Pacc->bf16 conversion in LDS).
// ---------------------------------------------------------------------------
__global__ __launch_bounds__(256) void k_scores(
    const unsigned short* __restrict__ embQ, const float* __restrict__ ssqQ,
    const float* __restrict__ Pacc, float* __restrict__ out) {
  __shared__ unsigned short Pl[4096 * 8];   // 64 KB bf16 fragment-packed
  int t = threadIdx.x;
#pragma unroll
  for (int i = 0; i < 16; ++i) {
    int c = t + 256 * i;          // chunk: class = c&63, kslot = c>>6
    int cls = c & 63, ks = c >> 6;
    const float* p = &Pacc[(size_t)cls * ED + ks * 8];
    fx4 p0 = *(const fx4*)p;
    fx4 p1 = *(const fx4*)(p + 4);
    ux8 bb;
    bb[0] = f2bf(p0.x); bb[1] = f2bf(p0.y); bb[2] = f2bf(p0.z); bb[3] = f2bf(p0.w);
    bb[4] = f2bf(p1.x); bb[5] = f2bf(p1.y); bb[6] = f2bf(p1.z); bb[7] = f2bf(p1.w);
    *(ux8*)&Pl[(size_t)c * 8] = bb;
  }
  __syncthreads();

  int w = t >> 6, lane = t & 63;
  int quad = lane >> 4, ml = lane & 15;
  int qrow0 = blockIdx.x * 64 + w * 16;

  fx4 acc[4];
#pragma unroll
  for (int i = 0; i < 4; ++i) acc[i] = fx4{0.f, 0.f, 0.f, 0.f};

#pragma unroll 4
  for (int ki = 0; ki < 16; ++ki) {
    sx8 a = *(const sx8*)&embQ[(size_t)(qrow0 + ml) * ED + ki * 32 + quad * 8];
#pragma unroll
    for (int nt = 0; nt < 4; ++nt) {
      sx8 b = *(const sx8*)&Pl[((ki * 4 + quad) * 64 + nt * 16 + ml) * 8];
      acc[nt] = __builtin_amdgcn_mfma_f32_16x16x32_bf16(a, b, acc[nt], 0, 0, 0);
    }
  }

#pragma unroll
  for (int r = 0; r < 4; ++r) {
    int qq = qrow0 + quad * 4 + r;
    float scale = 1.0f / fmaxf(sqrtf(ssqQ[qq]), 1e-12f);
    float s[4];
#pragma unroll
    for (int nt = 0; nt < 4; ++nt) s[nt] = acc[nt][r] * scale;
    float m = fmaxf(fmaxf(s[0], s[1]), fmaxf(s[2], s[3]));
#pragma unroll
    for (int off = 1; off < 16; off <<= 1) m = fmaxf(m, __shfl_xor(m, off, 16));
    float e[4], ssum = 0.f;
#pragma unroll
    for (int nt = 0; nt < 4; ++nt) { e[nt] = __expf(s[nt] - m); ssum += e[nt]; }
#pragma unroll
    for (int off = 1; off < 16; off <<= 1) ssum += __shfl_xor(ssum, off, 16);
    float inv = 1.0f / ssum;
#pragma unroll
    for (int nt = 0; nt < 4; ++nt)
      out[(size_t)qq * NC + nt * 16 + ml] = e[nt] * inv;
  }
}

// ---------------------------------------------------------------------------
extern "C" void kernel_launch(void* const* d_in, const int* in_sizes, int n_in,
                              void* d_out, int out_size, void* d_ws, size_t ws_size,
                              hipStream_t stream) {
  const float* Xs     = (const float*)d_in[0];  // support_data [8192,1024]
  const int*   labels = (const int*)d_in[1];    // support_labels [8192]
  const float* Xq     = (const float*)d_in[2];  // query_data [8192,1024]
  const float* W      = (const float*)d_in[3];  // W [1024,512]
  float* out = (float*)d_out;

  char* ws = (char*)d_ws;
  size_t off = 0;
  unsigned short* Wtp = (unsigned short*)(ws + off); off += (size_t)ED * KDIM * 2;    // 1 MB (fragment-packed)
  unsigned short* emb = (unsigned short*)(ws + off); off += (size_t)NTOT * ED * 2;    // 16 MB
  float* rowssq = (float*)(ws + off); off += (size_t)NTOT * 4;                        // 64 KB
  float* Pacc   = (float*)(ws + off); off += (size_t)NC * ED * 4;                     // 128 KB

  k_prep<<<256, 256, 0, stream>>>(W, Wtp, rowssq, Pacc);
  k_gemm_embed<<<512, 512, 0, stream>>>(Xs, Xq, Wtp, emb, rowssq);
  k_proto<<<dim3(32, 8), 256, 0, stream>>>(emb, rowssq, labels, Pacc);
  k_scores<<<NQ / 64, 256, 0, stream>>>(emb + (size_t)NS * ED, rowssq + NS, Pacc, out);
}

// Round 18
// 158.374 us; speedup vs baseline: 1.0232x; 1.0232x over previous
//
#include <hip/hip_runtime.h>
#include <hip/hip_bf16.h>

#define NS 8192
#define NQ 8192
#define NTOT 16384
#define KDIM 1024
#define ED 512
#define NC 64

typedef __attribute__((ext_vector_type(4))) float fx4;
typedef __attribute__((ext_vector_type(8))) short sx8;
typedef __attribute__((ext_vector_type(8))) unsigned short ux8;

__device__ __forceinline__ unsigned short f2bf(float f) {
  union { float f; unsigned u; } v; v.f = f;
  unsigned r = v.u + 0x7fffu + ((v.u >> 16) & 1u);   // RNE
  return (unsigned short)(r >> 16);
}
__device__ __forceinline__ float bf2f(unsigned short h) {
  union { unsigned u; float f; } v; v.u = ((unsigned)h) << 16;
  return v.f;
}

// ---------------------------------------------------------------------------
// K0: W -> Wtp, bf16 in MFMA B-FRAGMENT-PACKED order (unchanged).
// Also zeroes rowssq and Pacc.
// ---------------------------------------------------------------------------
__global__ __launch_bounds__(256) void k_prep(
    const float* __restrict__ W, unsigned short* __restrict__ Wtp,
    float* __restrict__ rowssq, float* __restrict__ Pacc) {
  int c = blockIdx.x * 256 + threadIdx.x;   // 0..65535
  int lane = c & 63;
  int j    = (c >> 6) & 3;
  int s2   = (c >> 8) & 1;
  int kt   = (c >> 9) & 15;
  int n64  = c >> 13;
  int quad = lane >> 4, ml = lane & 15;
  int n  = n64 * 64 + j * 16 + ml;
  int kb = kt * 64 + (s2 * 4 + quad) * 8;
  ux8 o;
#pragma unroll
  for (int e = 0; e < 8; ++e) o[e] = f2bf(W[(size_t)(kb + e) * ED + n]);
  *(ux8*)&Wtp[(size_t)c * 8] = o;
  if (c < NTOT) rowssq[c] = 0.f;
  if (c < NC * ED) Pacc[c] = 0.f;
}

// ---------------------------------------------------------------------------
// K1: emb = bf16(X) @ W + per-row ssq.
// R17 POST-MORTEM: 2 blocks/CU = 43.5us (worse than R16's 41): the TLP gain
// (+4.5us) was outweighed by doubled per-wave B re-reads (256->512MB L2).
// Conclusion: R16's 64-rows/wave geometry is B-traffic-optimal; the residual
// serial term is loadB issued and consumed INSIDE the same step (8x1KB of
// L2/L3 latency + L1-port serialization on the critical path x16 steps).
// R13's B-prefetch null was measured in the X-re-read-bound regime — rule
// #23: uninterpretable here.
// R18 = R16 + B depth-1 register double-buffer (NAMED bfA/bfB, rule #20):
// loadB(kt+1) issues at step kt, crosses one barrier as dangling reg-loads,
// consumed at kt+1 — a full step of cover. VGPR 60 -> ~95 (cap 256 at
// launch_bounds(512,2)). Geometry/grid byte-identical to R16.
// Falsifiable: B-latency theory => 33-38us; invariant ~41 => structural
// step cost -> declare practical ceiling (harness fill floor ~100us).
// ---------------------------------------------------------------------------
__global__ __launch_bounds__(512, 2) void k_gemm_embed(
    const float* __restrict__ Xs, const float* __restrict__ Xq,
    const unsigned short* __restrict__ Wtp,
    unsigned short* __restrict__ emb, float* __restrict__ rowssq) {
  __shared__ unsigned short Ash[2][64 * 8 * 8];  // 8 KB per buf, [m*8+slot][8]

  int m_blk = blockIdx.x;          // 0..255, unique 64-row tile
  const float* Xsrc = (m_blk < 128)
      ? (Xs + (size_t)m_blk * 64 * KDIM)
      : (Xq + (size_t)(m_blk - 128) * 64 * KDIM);

  int t = threadIdx.x;             // 0..511
  int lane = t & 63, w = t >> 6;   // w = 0..7: 64-col slice (= n64 unit)
  int quad = lane >> 4, ml = lane & 15;

  // per-wave B fragment base: chunk (w*8192 + lane), element *8
  const unsigned short* Bbase = Wtp + ((size_t)w * 8192 + lane) * 8;

  fx4 acc[4][4];                   // wave's 64x64 output
#pragma unroll
  for (int i = 0; i < 4; ++i)
#pragma unroll
    for (int j = 0; j < 4; ++j) acc[i][j] = fx4{0.f, 0.f, 0.f, 0.f};

  fx4 avA[2], avB[2];              // NAMED A double-buffer, 1 chunk/thread
  sx8 bfA[2][4], bfB[2][4];        // NAMED B double-buffer (rule #20)

  int am = t >> 3, akq = t & 7;    // this thread's A row / k-octet

  auto loadA = [&](int kt, fx4 (&av)[2]) {
    const float* g = &Xsrc[(size_t)am * KDIM + kt * 64 + akq * 8];
    av[0] = *(const fx4*)g;
    av[1] = *(const fx4*)(g + 4);
  };
  auto writeA = [&](const fx4 (&av)[2], int bbuf) {
    ux8 o;
    o[0] = f2bf(av[0].x); o[1] = f2bf(av[0].y);
    o[2] = f2bf(av[0].z); o[3] = f2bf(av[0].w);
    o[4] = f2bf(av[1].x); o[5] = f2bf(av[1].y);
    o[6] = f2bf(av[1].z); o[7] = f2bf(av[1].w);
    *(ux8*)&Ash[bbuf][((am * 8) + (akq ^ (am & 7))) * 8] = o;  // slot swizzle
  };
  auto loadB = [&](int kt, sx8 (&bf)[2][4]) {
#pragma unroll
    for (int s2 = 0; s2 < 2; ++s2)
#pragma unroll
      for (int j = 0; j < 4; ++j)
        bf[s2][j] = *(const sx8*)&Bbase[(size_t)(kt * 512 + s2 * 256 + j * 64) * 8];
  };
  auto compute = [&](int b, const sx8 (&bf)[2][4]) {
#pragma unroll
    for (int s2 = 0; s2 < 2; ++s2) {
      int kq = s2 * 4 + quad;
      sx8 af[4];
#pragma unroll
      for (int i = 0; i < 4; ++i) {
        int row = i * 16 + ml;
        af[i] = *(const sx8*)&Ash[b][(row * 8 + (kq ^ (row & 7))) * 8];
      }
#pragma unroll
      for (int i = 0; i < 4; ++i)
#pragma unroll
        for (int j = 0; j < 4; ++j)
          acc[i][j] = __builtin_amdgcn_mfma_f32_16x16x32_bf16(af[i], bf[s2][j], acc[i][j], 0, 0, 0);
    }
  };
  auto sync_step = [&]() {
    __builtin_amdgcn_sched_barrier(0);
    asm volatile("s_waitcnt lgkmcnt(0)" ::: "memory");
    __builtin_amdgcn_s_barrier();
    __builtin_amdgcn_sched_barrier(0);
  };

  // prologue: B(0)->bfA; A(0)->avA->Ash[0]; A(1)->avB stays in flight
  loadB(0, bfA);
  loadA(0, avA);
  loadA(1, avB);
  writeA(avA, 0);
  sync_step();

  for (int it = 0; it < 8; ++it) {
    int kt0 = it * 2;
    {
      // even step kt0: compute Ash[0] with bfA=B(kt0)
      loadB(kt0 + 1, bfB);                       // B prefetch depth-1
      loadA(kt0 + 2 < 16 ? kt0 + 2 : 15, avA);   // A prefetch depth-2
      compute(0, bfA);
      writeA(avB, 1);
      sync_step();
    }
    {
      // odd step kt0+1: compute Ash[1] with bfB=B(kt0+1)
      loadB(kt0 + 2 < 16 ? kt0 + 2 : 15, bfA);
      loadA(kt0 + 3 < 16 ? kt0 + 3 : 15, avB);
      compute(1, bfB);
      writeA(avA, 0);
      sync_step();
    }
  }

  // epilogue: emb store + row-ssq partial (shfl width-16 + 1 atomic per row)
  int grow = m_blk * 64;
  int gcol = w * 64;
#pragma unroll
  for (int i = 0; i < 4; ++i) {
#pragma unroll
    for (int r = 0; r < 4; ++r) {
      int mrow = grow + i * 16 + quad * 4 + r;
      float p = 0.f;
#pragma unroll
      for (int j = 0; j < 4; ++j) {
        emb[(size_t)mrow * ED + gcol + j * 16 + ml] = f2bf(acc[i][j][r]);
        p += acc[i][j][r] * acc[i][j][r];
      }
#pragma unroll
      for (int off = 1; off < 16; off <<= 1) p += __shfl_xor(p, off, 16);
      if (ml == 0) atomicAdd(&rowssq[mrow], p);
    }
  }
}

// ---------------------------------------------------------------------------
// K2: per-class sums of (emb_s/||s||), LDS-accumulated, global-atomic flush
// into Pacc[NC][ED] (unchanged).
// ---------------------------------------------------------------------------
__global__ __launch_bounds__(256) void k_proto(
    const unsigned short* __restrict__ embS, const float* __restrict__ rowssq,
    const int* __restrict__ labels, float* __restrict__ Pacc) {
  __shared__ float Pl[NC * 64];  // 16 KB: [class][dim-within-slice]
  int t = threadIdx.x;
#pragma unroll
  for (int i = 0; i < 16; ++i) Pl[i * 256 + t] = 0.f;
  __syncthreads();

  int w = t >> 6, lane = t & 63;
  int ds = blockIdx.y;            // dim slice: dims [ds*64, ds*64+64)
  int row0 = blockIdx.x * 256;    // 32 chunks of 256 rows
#pragma unroll 4
  for (int r = w; r < 256; r += 4) {
    int row = row0 + r;
    int lbl = labels[row];
    float scale = 1.0f / fmaxf(sqrtf(rowssq[row]), 1e-12f);
    float v = bf2f(embS[(size_t)row * ED + ds * 64 + lane]) * scale;
    atomicAdd(&Pl[lbl * 64 + lane], v);
  }
  __syncthreads();

#pragma unroll
  for (int i = 0; i < 16; ++i) {
    int idx = i * 256 + t;        // class = idx>>6, dim-in-slice = idx&63
    atomicAdd(&Pacc[(size_t)(idx >> 6) * ED + ds * 64 + (idx & 63)], Pl[idx]);
  }
}

// ---------------------------------------------------------------------------
// K3: class_scores = (emb_q @ P^T) / ||q|| + fused softmax (unchanged R13:
// 128 blocks x 256 threads, block-shared Pacc->bf16 conversion in LDS).
// ---------------------------------------------------------------------------
__global__ __launch_bounds__(256) void k_scores(
    const unsigned short* __restrict__ embQ, const float* __restrict__ ssqQ,
    const float* __restrict__ Pacc, float* __restrict__ out) {
  __shared__ unsigned short Pl[4096 * 8];   // 64 KB bf16 fragment-packed
  int t = threadIdx.x;
#pragma unroll
  for (int i = 0; i < 16; ++i) {
    int c = t + 256 * i;          // chunk: class = c&63, kslot = c>>6
    int cls = c & 63, ks = c >> 6;
    const float* p = &Pacc[(size_t)cls * ED + ks * 8];
    fx4 p0 = *(const fx4*)p;
    fx4 p1 = *(const fx4*)(p + 4);
    ux8 bb;
    bb[0] = f2bf(p0.x); bb[1] = f2bf(p0.y); bb[2] = f2bf(p0.z); bb[3] = f2bf(p0.w);
    bb[4] = f2bf(p1.x); bb[5] = f2bf(p1.y); bb[6] = f2bf(p1.z); bb[7] = f2bf(p1.w);
    *(ux8*)&Pl[(size_t)c * 8] = bb;
  }
  __syncthreads();

  int w = t >> 6, lane = t & 63;
  int quad = lane >> 4, ml = lane & 15;
  int qrow0 = blockIdx.x * 64 + w * 16;

  fx4 acc[4];
#pragma unroll
  for (int i = 0; i < 4; ++i) acc[i] = fx4{0.f, 0.f, 0.f, 0.f};

#pragma unroll 4
  for (int ki = 0; ki < 16; ++ki) {
    sx8 a = *(const sx8*)&embQ[(size_t)(qrow0 + ml) * ED + ki * 32 + quad * 8];
#pragma unroll
    for (int nt = 0; nt < 4; ++nt) {
      sx8 b = *(const sx8*)&Pl[((ki * 4 + quad) * 64 + nt * 16 + ml) * 8];
      acc[nt] = __builtin_amdgcn_mfma_f32_16x16x32_bf16(a, b, acc[nt], 0, 0, 0);
    }
  }

#pragma unroll
  for (int r = 0; r < 4; ++r) {
    int qq = qrow0 + quad * 4 + r;
    float scale = 1.0f / fmaxf(sqrtf(ssqQ[qq]), 1e-12f);
    float s[4];
#pragma unroll
    for (int nt = 0; nt < 4; ++nt) s[nt] = acc[nt][r] * scale;
    float m = fmaxf(fmaxf(s[0], s[1]), fmaxf(s[2], s[3]));
#pragma unroll
    for (int off = 1; off < 16; off <<= 1) m = fmaxf(m, __shfl_xor(m, off, 16));
    float e[4], ssum = 0.f;
#pragma unroll
    for (int nt = 0; nt < 4; ++nt) { e[nt] = __expf(s[nt] - m); ssum += e[nt]; }
#pragma unroll
    for (int off = 1; off < 16; off <<= 1) ssum += __shfl_xor(ssum, off, 16);
    float inv = 1.0f / ssum;
#pragma unroll
    for (int nt = 0; nt < 4; ++nt)
      out[(size_t)qq * NC + nt * 16 + ml] = e[nt] * inv;
  }
}

// ---------------------------------------------------------------------------
extern "C" void kernel_launch(void* const* d_in, const int* in_sizes, int n_in,
                              void* d_out, int out_size, void* d_ws, size_t ws_size,
                              hipStream_t stream) {
  const float* Xs     = (const float*)d_in[0];  // support_data [8192,1024]
  const int*   labels = (const int*)d_in[1];    // support_labels [8192]
  const float* Xq     = (const float*)d_in[2];  // query_data [8192,1024]
  const float* W      = (const float*)d_in[3];  // W [1024,512]
  float* out = (float*)d_out;

  char* ws = (char*)d_ws;
  size_t off = 0;
  unsigned short* Wtp = (unsigned short*)(ws + off); off += (size_t)ED * KDIM * 2;    // 1 MB (fragment-packed)
  unsigned short* emb = (unsigned short*)(ws + off); off += (size_t)NTOT * ED * 2;    // 16 MB
  float* rowssq = (float*)(ws + off); off += (size_t)NTOT * 4;                        // 64 KB
  float* Pacc   = (float*)(ws + off); off += (size_t)NC * ED * 4;                     // 128 KB

  k_prep<<<256, 256, 0, stream>>>(W, Wtp, rowssq, Pacc);
  k_gemm_embed<<<256, 512, 0, stream>>>(Xs, Xq, Wtp, emb, rowssq);
  k_proto<<<dim3(32, 8), 256, 0, stream>>>(emb, rowssq, labels, Pacc);
  k_scores<<<NQ / 64, 256, 0, stream>>>(emb + (size_t)NS * ED, rowssq + NS, Pacc, out);
}

// Round 19
// 151.523 us; speedup vs baseline: 1.0695x; 1.0452x over previous
//
#include <hip/hip_runtime.h>
#include <hip/hip_bf16.h>

#define NS 8192
#define NQ 8192
#define NTOT 16384
#define KDIM 1024
#define ED 512
#define NC 64

typedef __attribute__((ext_vector_type(4))) float fx4;
typedef __attribute__((ext_vector_type(8))) short sx8;
typedef __attribute__((ext_vector_type(8))) unsigned short ux8;

__device__ __forceinline__ unsigned short f2bf(float f) {
  union { float f; unsigned u; } v; v.f = f;
  unsigned r = v.u + 0x7fffu + ((v.u >> 16) & 1u);   // RNE
  return (unsigned short)(r >> 16);
}
__device__ __forceinline__ float bf2f(unsigned short h) {
  union { unsigned u; float f; } v; v.u = ((unsigned)h) << 16;
  return v.f;
}

// ---------------------------------------------------------------------------
// K0: W -> Wtp, bf16 in MFMA B-FRAGMENT-PACKED order (unchanged).
// Also zeroes rowssq and Pacc.
// ---------------------------------------------------------------------------
__global__ __launch_bounds__(256) void k_prep(
    const float* __restrict__ W, unsigned short* __restrict__ Wtp,
    float* __restrict__ rowssq, float* __restrict__ Pacc) {
  int c = blockIdx.x * 256 + threadIdx.x;   // 0..65535
  int lane = c & 63;
  int j    = (c >> 6) & 3;
  int s2   = (c >> 8) & 1;
  int kt   = (c >> 9) & 15;
  int n64  = c >> 13;
  int quad = lane >> 4, ml = lane & 15;
  int n  = n64 * 64 + j * 16 + ml;
  int kb = kt * 64 + (s2 * 4 + quad) * 8;
  ux8 o;
#pragma unroll
  for (int e = 0; e < 8; ++e) o[e] = f2bf(W[(size_t)(kb + e) * ED + n]);
  *(ux8*)&Wtp[(size_t)c * 8] = o;
  if (c < NTOT) rowssq[c] = 0.f;
  if (c < NC * ED) Pacc[c] = 0.f;
}

// ---------------------------------------------------------------------------
// K1: emb = bf16(X) @ W + per-row ssq.
// R18 POST-MORTEM: B depth-1 prefetch landed — k_gemm dropped below the
// 41us harness fill (out of top-5), ~36us, matching the 33-38 prediction.
// Per-step arithmetic: 36us/16 steps = 2.3us/step; pipe sum (MFMA 0.13 +
// LDS 0.26 + B/L1 0.5) = 0.9us => ~1.4us/step of barrier-arrival + drain
// overhead at 8-wave-lockstep 1 block/CU. Geometry is cornered (X-once
// needs full-width blocks; B-min needs 64 rows/wave => exactly 1 block/CU)
// so the only lever is FEWER STEPS. R15's BK=128 null was measured in the
// X-re-read-bound regime — rule #23: uninterpretable for this regime.
// R19 = R18 + BK=128 (8 steps): Ash = two verified 64-k halves per dbuf
// (R15 layout); A-stage 2 chunks/thread; B dbuf [4][4] depth-1. VGPR ~230
// (cap 256 @ launch_bounds(512,2)); spill tripwire: WRITE_SIZE > 18.4MB.
// Falsifiable: step-overhead theory => 26-30us; invariant/worse => revert
// R18 and declare practical plateau (harness fill floor ~100us).
// ---------------------------------------------------------------------------
__global__ __launch_bounds__(512, 2) void k_gemm_embed(
    const float* __restrict__ Xs, const float* __restrict__ Xq,
    const unsigned short* __restrict__ Wtp,
    unsigned short* __restrict__ emb, float* __restrict__ rowssq) {
  __shared__ unsigned short Ash[2][2][64 * 8 * 8];  // [dbuf][half] 8 KB each

  int m_blk = blockIdx.x;          // 0..255, unique 64-row tile
  const float* Xsrc = (m_blk < 128)
      ? (Xs + (size_t)m_blk * 64 * KDIM)
      : (Xq + (size_t)(m_blk - 128) * 64 * KDIM);

  int t = threadIdx.x;             // 0..511
  int lane = t & 63, w = t >> 6;   // w = 0..7: 64-col slice (= n64 unit)
  int quad = lane >> 4, ml = lane & 15;

  // per-wave B fragment base: chunk (w*8192 + lane), element *8
  const unsigned short* Bbase = Wtp + ((size_t)w * 8192 + lane) * 8;

  fx4 acc[4][4];                   // wave's 64x64 output
#pragma unroll
  for (int i = 0; i < 4; ++i)
#pragma unroll
    for (int j = 0; j < 4; ++j) acc[i][j] = fx4{0.f, 0.f, 0.f, 0.f};

  fx4 avA[2][2], avB[2][2];        // NAMED A double-buffer: [half][8 floats]
  sx8 bfA[4][4], bfB[4][4];        // NAMED B double-buffer (rule #20)

  int am = t >> 3, akq = t & 7;    // this thread's A row / octet-within-half

  auto loadA = [&](int kt, fx4 (&av)[2][2]) {   // kt in 128-k steps (0..7)
#pragma unroll
    for (int h = 0; h < 2; ++h) {
      const float* g = &Xsrc[(size_t)am * KDIM + kt * 128 + h * 64 + akq * 8];
      av[h][0] = *(const fx4*)g;
      av[h][1] = *(const fx4*)(g + 4);
    }
  };
  auto writeA = [&](const fx4 (&av)[2][2], int bbuf) {
#pragma unroll
    for (int h = 0; h < 2; ++h) {
      ux8 o;
      o[0] = f2bf(av[h][0].x); o[1] = f2bf(av[h][0].y);
      o[2] = f2bf(av[h][0].z); o[3] = f2bf(av[h][0].w);
      o[4] = f2bf(av[h][1].x); o[5] = f2bf(av[h][1].y);
      o[6] = f2bf(av[h][1].z); o[7] = f2bf(av[h][1].w);
      *(ux8*)&Ash[bbuf][h][((am * 8) + (akq ^ (am & 7))) * 8] = o;  // swizzle
    }
  };
  auto loadB = [&](int kt, sx8 (&bf)[4][4]) {   // kt in 128-k steps
#pragma unroll
    for (int g = 0; g < 4; ++g) {               // 4 k-slices of 32
      int kt64 = 2 * kt + (g >> 1);
      int s2p = g & 1;
#pragma unroll
      for (int j = 0; j < 4; ++j)
        bf[g][j] = *(const sx8*)&Bbase[(size_t)(kt64 * 512 + s2p * 256 + j * 64) * 8];
    }
  };
  auto compute = [&](int b, const sx8 (&bf)[4][4]) {
#pragma unroll
    for (int g = 0; g < 4; ++g) {
      int kq16 = g * 4 + quad;                  // global octet 0..15
      int half = kq16 >> 3, oct = kq16 & 7;
      sx8 af[4];
#pragma unroll
      for (int i = 0; i < 4; ++i) {
        int row = i * 16 + ml;
        af[i] = *(const sx8*)&Ash[b][half][(row * 8 + (oct ^ (row & 7))) * 8];
      }
#pragma unroll
      for (int i = 0; i < 4; ++i)
#pragma unroll
        for (int j = 0; j < 4; ++j)
          acc[i][j] = __builtin_amdgcn_mfma_f32_16x16x32_bf16(af[i], bf[g][j], acc[i][j], 0, 0, 0);
    }
  };
  auto sync_step = [&]() {
    __builtin_amdgcn_sched_barrier(0);
    asm volatile("s_waitcnt lgkmcnt(0)" ::: "memory");
    __builtin_amdgcn_s_barrier();
    __builtin_amdgcn_sched_barrier(0);
  };

  // prologue: B(0)->bfA; A(0)->avA->Ash[0]; A(1)->avB stays in flight
  loadB(0, bfA);
  loadA(0, avA);
  loadA(1, avB);
  writeA(avA, 0);
  sync_step();

  for (int it = 0; it < 4; ++it) {              // 8 steps of BK=128
    int kt0 = it * 2;
    {
      // even step kt0: compute Ash[0] with bfA=B(kt0)
      loadB(kt0 + 1, bfB);                      // B prefetch depth-1
      loadA(kt0 + 2 < 8 ? kt0 + 2 : 7, avA);    // A prefetch depth-2
      compute(0, bfA);
      writeA(avB, 1);
      sync_step();
    }
    {
      // odd step kt0+1: compute Ash[1] with bfB=B(kt0+1)
      loadB(kt0 + 2 < 8 ? kt0 + 2 : 7, bfA);
      loadA(kt0 + 3 < 8 ? kt0 + 3 : 7, avB);
      compute(1, bfB);
      writeA(avA, 0);
      sync_step();
    }
  }

  // epilogue: emb store + row-ssq partial (shfl width-16 + 1 atomic per row)
  int grow = m_blk * 64;
  int gcol = w * 64;
#pragma unroll
  for (int i = 0; i < 4; ++i) {
#pragma unroll
    for (int r = 0; r < 4; ++r) {
      int mrow = grow + i * 16 + quad * 4 + r;
      float p = 0.f;
#pragma unroll
      for (int j = 0; j < 4; ++j) {
        emb[(size_t)mrow * ED + gcol + j * 16 + ml] = f2bf(acc[i][j][r]);
        p += acc[i][j][r] * acc[i][j][r];
      }
#pragma unroll
      for (int off = 1; off < 16; off <<= 1) p += __shfl_xor(p, off, 16);
      if (ml == 0) atomicAdd(&rowssq[mrow], p);
    }
  }
}

// ---------------------------------------------------------------------------
// K2: per-class sums of (emb_s/||s||), LDS-accumulated, global-atomic flush
// into Pacc[NC][ED] (unchanged).
// ---------------------------------------------------------------------------
__global__ __launch_bounds__(256) void k_proto(
    const unsigned short* __restrict__ embS, const float* __restrict__ rowssq,
    const int* __restrict__ labels, float* __restrict__ Pacc) {
  __shared__ float Pl[NC * 64];  // 16 KB: [class][dim-within-slice]
  int t = threadIdx.x;
#pragma unroll
  for (int i = 0; i < 16; ++i) Pl[i * 256 + t] = 0.f;
  __syncthreads();

  int w = t >> 6, lane = t & 63;
  int ds = blockIdx.y;            // dim slice: dims [ds*64, ds*64+64)
  int row0 = blockIdx.x * 256;    // 32 chunks of 256 rows
#pragma unroll 4
  for (int r = w; r < 256; r += 4) {
    int row = row0 + r;
    int lbl = labels[row];
    float scale = 1.0f / fmaxf(sqrtf(rowssq[row]), 1e-12f);
    float v = bf2f(embS[(size_t)row * ED + ds * 64 + lane]) * scale;
    atomicAdd(&Pl[lbl * 64 + lane], v);
  }
  __syncthreads();

#pragma unroll
  for (int i = 0; i < 16; ++i) {
    int idx = i * 256 + t;        // class = idx>>6, dim-in-slice = idx&63
    atomicAdd(&Pacc[(size_t)(idx >> 6) * ED + ds * 64 + (idx & 63)], Pl[idx]);
  }
}

// ---------------------------------------------------------------------------
// K3: class_scores = (emb_q @ P^T) / ||q|| + fused softmax (unchanged R13:
// 128 blocks x 256 threads, block-shared Pacc->bf16 conversion in LDS).
// ---------------------------------------------------------------------------
__global__ __launch_bounds__(256) void k_scores(
    const unsigned short* __restrict__ embQ, const float* __restrict__ ssqQ,
    const float* __restrict__ Pacc, float* __restrict__ out) {
  __shared__ unsigned short Pl[4096 * 8];   // 64 KB bf16 fragment-packed
  int t = threadIdx.x;
#pragma unroll
  for (int i = 0; i < 16; ++i) {
    int c = t + 256 * i;          // chunk: class = c&63, kslot = c>>6
    int cls = c & 63, ks = c >> 6;
    const float* p = &Pacc[(size_t)cls * ED + ks * 8];
    fx4 p0 = *(const fx4*)p;
    fx4 p1 = *(const fx4*)(p + 4);
    ux8 bb;
    bb[0] = f2bf(p0.x); bb[1] = f2bf(p0.y); bb[2] = f2bf(p0.z); bb[3] = f2bf(p0.w);
    bb[4] = f2bf(p1.x); bb[5] = f2bf(p1.y); bb[6] = f2bf(p1.z); bb[7] = f2bf(p1.w);
    *(ux8*)&Pl[(size_t)c * 8] = bb;
  }
  __syncthreads();

  int w = t >> 6, lane = t & 63;
  int quad = lane >> 4, ml = lane & 15;
  int qrow0 = blockIdx.x * 64 + w * 16;

  fx4 acc[4];
#pragma unroll
  for (int i = 0; i < 4; ++i) acc[i] = fx4{0.f, 0.f, 0.f, 0.f};

#pragma unroll 4
  for (int ki = 0; ki < 16; ++ki) {
    sx8 a = *(const sx8*)&embQ[(size_t)(qrow0 + ml) * ED + ki * 32 + quad * 8];
#pragma unroll
    for (int nt = 0; nt < 4; ++nt) {
      sx8 b = *(const sx8*)&Pl[((ki * 4 + quad) * 64 + nt * 16 + ml) * 8];
      acc[nt] = __builtin_amdgcn_mfma_f32_16x16x32_bf16(a, b, acc[nt], 0, 0, 0);
    }
  }

#pragma unroll
  for (int r = 0; r < 4; ++r) {
    int qq = qrow0 + quad * 4 + r;
    float scale = 1.0f / fmaxf(sqrtf(ssqQ[qq]), 1e-12f);
    float s[4];
#pragma unroll
    for (int nt = 0; nt < 4; ++nt) s[nt] = acc[nt][r] * scale;
    float m = fmaxf(fmaxf(s[0], s[1]), fmaxf(s[2], s[3]));
#pragma unroll
    for (int off = 1; off < 16; off <<= 1) m = fmaxf(m, __shfl_xor(m, off, 16));
    float e[4], ssum = 0.f;
#pragma unroll
    for (int nt = 0; nt < 4; ++nt) { e[nt] = __expf(s[nt] - m); ssum += e[nt]; }
#pragma unroll
    for (int off = 1; off < 16; off <<= 1) ssum += __shfl_xor(ssum, off, 16);
    float inv = 1.0f / ssum;
#pragma unroll
    for (int nt = 0; nt < 4; ++nt)
      out[(size_t)qq * NC + nt * 16 + ml] = e[nt] * inv;
  }
}

// ---------------------------------------------------------------------------
extern "C" void kernel_launch(void* const* d_in, const int* in_sizes, int n_in,
                              void* d_out, int out_size, void* d_ws, size_t ws_size,
                              hipStream_t stream) {
  const float* Xs     = (const float*)d_in[0];  // support_data [8192,1024]
  const int*   labels = (const int*)d_in[1];    // support_labels [8192]
  const float* Xq     = (const float*)d_in[2];  // query_data [8192,1024]
  const float* W      = (const float*)d_in[3];  // W [1024,512]
  float* out = (float*)d_out;

  char* ws = (char*)d_ws;
  size_t off = 0;
  unsigned short* Wtp = (unsigned short*)(ws + off); off += (size_t)ED * KDIM * 2;    // 1 MB (fragment-packed)
  unsigned short* emb = (unsigned short*)(ws + off); off += (size_t)NTOT * ED * 2;    // 16 MB
  float* rowssq = (float*)(ws + off); off += (size_t)NTOT * 4;                        // 64 KB
  float* Pacc   = (float*)(ws + off); off += (size_t)NC * ED * 4;                     // 128 KB

  k_prep<<<256, 256, 0, stream>>>(W, Wtp, rowssq, Pacc);
  k_gemm_embed<<<256, 512, 0, stream>>>(Xs, Xq, Wtp, emb, rowssq);
  k_proto<<<dim3(32, 8), 256, 0, stream>>>(emb, rowssq, labels, Pacc);
  k_scores<<<NQ / 64, 256, 0, stream>>>(emb + (size_t)NS * ED, rowssq + NS, Pacc, out);
}